// Round 2
// baseline (1236.901 us; speedup 1.0000x reference)
//
#include <hip/hip_runtime.h>
#include <hip/hip_bf16.h>

// Problem constants (B=4, L=2048, D=1024, H=4096, E=8, K=2)
#define NTOK   8192
#define DDIM   1024
#define HDIM   4096
#define NEXP   8
#define CAP    8192
#define NSLOT  (NTOK * 2)

// GEMM tiling (m97 structure + T3 minimum-2-phase double buffer)
#define BM 128
#define BN 128
#define BK 64

typedef __attribute__((ext_vector_type(8))) short bf16x8;
typedef __attribute__((ext_vector_type(4))) float f32x4;

// async global->LDS, 16B per lane; LDS dest = wave-uniform base + lane*16
#define GLD16(g, l) __builtin_amdgcn_global_load_lds(                          \
    (const __attribute__((address_space(1))) void*)(g),                        \
    (__attribute__((address_space(3))) void*)(l), 16, 0, 0)

// ---------------- Router: logits -> top2 -> softmax -> expert lists ----------------
__global__ __launch_bounds__(64) void router_kernel(
    const float* __restrict__ xs, const float* __restrict__ gw,
    int* __restrict__ counts, int* __restrict__ toklist, float* __restrict__ wglist)
{
    const int n = blockIdx.x;
    const int lane = threadIdx.x;
    const float* xrow = xs + (size_t)n * DDIM;
    float xv[16];
#pragma unroll
    for (int j = 0; j < 16; ++j) xv[j] = xrow[lane + 64 * j];
    float logit[NEXP];
#pragma unroll
    for (int e = 0; e < NEXP; ++e) {
        float p = 0.f;
        const float* gr = gw + e * DDIM;
#pragma unroll
        for (int j = 0; j < 16; ++j) p += xv[j] * gr[lane + 64 * j];
#pragma unroll
        for (int off = 32; off >= 1; off >>= 1) p += __shfl_xor(p, off);
        logit[e] = p;
    }
    if (lane == 0) {
        int i0 = 0;
#pragma unroll
        for (int e = 1; e < NEXP; ++e) if (logit[e] > logit[i0]) i0 = e;
        int i1 = (i0 == 0) ? 1 : 0;
#pragma unroll
        for (int e = 0; e < NEXP; ++e) if (e != i0 && logit[e] > logit[i1]) i1 = e;
        float ex = expf(logit[i1] - logit[i0]);
        float w0 = 1.f / (1.f + ex);
        float w1 = ex * w0;
        int p0 = atomicAdd(&counts[i0], 1);
        toklist[i0 * CAP + p0] = n;
        wglist[i0 * CAP + p0] = w0;
        int p1 = atomicAdd(&counts[i1], 1);
        toklist[i1 * CAP + p1] = n;
        wglist[i1 * CAP + p1] = w1;
    }
}

__global__ void prefix_kernel(const int* __restrict__ counts, int* __restrict__ base)
{
    if (threadIdx.x == 0 && blockIdx.x == 0) {
        int s = 0;
        for (int e = 0; e < NEXP; ++e) { base[e] = s; s += counts[e]; }
    }
}

// ---------------- xs fp32 -> bf16 ----------------
__global__ __launch_bounds__(256) void cvt_xs_kernel(
    const float* __restrict__ xs, __hip_bfloat16* __restrict__ xsb)
{
    const size_t i = ((size_t)blockIdx.x * 256 + threadIdx.x) * 8;
    const float4 a = *(const float4*)(xs + i);
    const float4 b = *(const float4*)(xs + i + 4);
    __hip_bfloat16 o[8];
    o[0] = __float2bfloat16(a.x); o[1] = __float2bfloat16(a.y);
    o[2] = __float2bfloat16(a.z); o[3] = __float2bfloat16(a.w);
    o[4] = __float2bfloat16(b.x); o[5] = __float2bfloat16(b.y);
    o[6] = __float2bfloat16(b.z); o[7] = __float2bfloat16(b.w);
    *(bf16x8*)(xsb + i) = *(bf16x8*)o;
}

// ---------------- per-expert transpose fp32 (RxC) -> bf16 (CxR) ----------------
__global__ __launch_bounds__(256) void transpose_bf16_kernel(
    const float* __restrict__ src, __hip_bfloat16* __restrict__ dst, int R, int C)
{
    __shared__ __hip_bfloat16 t[64][72];
    const int e = blockIdx.z;
    src += (size_t)e * R * C;
    dst += (size_t)e * R * C;
    const int r0 = blockIdx.y * 64, c0 = blockIdx.x * 64;
    const int tid = threadIdx.x;
#pragma unroll
    for (int i = 0; i < 4; ++i) {
        int r = (tid >> 4) + 16 * i;
        int c = (tid & 15) * 4;
        float4 v = *(const float4*)(src + (size_t)(r0 + r) * C + c0 + c);
        t[r][c + 0] = __float2bfloat16(v.x);
        t[r][c + 1] = __float2bfloat16(v.y);
        t[r][c + 2] = __float2bfloat16(v.z);
        t[r][c + 3] = __float2bfloat16(v.w);
    }
    __syncthreads();
#pragma unroll
    for (int i = 0; i < 4; ++i) {
        int c = (tid >> 4) + 16 * i;
        int r = (tid & 15) * 4;
        __hip_bfloat16 o[4] = { t[r][c], t[r + 1][c], t[r + 2][c], t[r + 3][c] };
        *(short4*)(dst + (size_t)(c0 + c) * R + r0 + r) = *(short4*)o;
    }
}

// ---------------- GEMM1: h[slot][:] = relu(x[tok] @ w1[e]), bf16 out ----------------
// 1-D grid (16384 blocks). XCD-bijective remap, expert-major chunking.
// T3 min-2-phase: STAGE(t+1) into other buffer BEFORE compute(t); one barrier/step.
__global__ __launch_bounds__(256) void gemm1_kernel(
    const __hip_bfloat16* __restrict__ xsb, const __hip_bfloat16* __restrict__ w1t,
    const int* __restrict__ counts, const int* __restrict__ base,
    const int* __restrict__ toklist, __hip_bfloat16* __restrict__ h)
{
    const unsigned bidx = blockIdx.x;
    const unsigned w = (bidx & 7u) * 2048u + (bidx >> 3);   // bijective: 16384 % 8 == 0
    const int e  = w >> 11;             // 0..7  (expert == XCD)
    const int m0 = ((w >> 5) & 63) * BM;
    const int n0 = (w & 31) * BN;

    const int cnt = counts[e];
    if (m0 >= cnt) return;

    __shared__ __align__(16) __hip_bfloat16 As[2][BM * BK];
    __shared__ __align__(16) __hip_bfloat16 Bs[2][BN * BK];
    __shared__ int tok_s[BM];

    const int tid = threadIdx.x;
    if (tid < BM) tok_s[tid] = toklist[e * CAP + min(m0 + tid, cnt - 1)];
    __syncthreads();

    const int wave = tid >> 6;
    const int lane = tid & 63;
    const int lrow = lane >> 3;          // 0..7
    const int lcol = (lane & 7) * 8;     // k elems
    const __hip_bfloat16* w1e = w1t + (size_t)e * HDIM * DDIM;

    const __hip_bfloat16* srcA[4];
    const __hip_bfloat16* srcB[4];
#pragma unroll
    for (int c = 0; c < 4; ++c) {
        int r = wave * 32 + c * 8 + lrow;
        srcA[c] = xsb + (size_t)tok_s[r] * DDIM + lcol;
        srcB[c] = w1e + (size_t)(n0 + r) * DDIM + lcol;
    }

    f32x4 acc[4][4];
#pragma unroll
    for (int i = 0; i < 4; ++i)
#pragma unroll
        for (int j = 0; j < 4; ++j) acc[i][j] = (f32x4){0.f, 0.f, 0.f, 0.f};

    const int wm = (wave >> 1) * 64;
    const int wn = (wave & 1) * 64;
    const int l15 = lane & 15;
    const int quad = lane >> 4;

    const int NT = DDIM / BK;   // 16
    // prologue: stage tile 0, drain
#pragma unroll
    for (int c = 0; c < 4; ++c) {
        GLD16(srcA[c], &As[0][(wave * 32 + c * 8) * BK]);
        GLD16(srcB[c], &Bs[0][(wave * 32 + c * 8) * BK]);
    }
    __syncthreads();

    for (int t = 0; t < NT; ++t) {
        const int cur = t & 1;
        if (t + 1 < NT) {
            const int nk = (t + 1) * BK;
#pragma unroll
            for (int c = 0; c < 4; ++c) {
                GLD16(srcA[c] + nk, &As[cur ^ 1][(wave * 32 + c * 8) * BK]);
                GLD16(srcB[c] + nk, &Bs[cur ^ 1][(wave * 32 + c * 8) * BK]);
            }
        }
#pragma unroll
        for (int kk = 0; kk < 2; ++kk) {
            bf16x8 a[4], b[4];
#pragma unroll
            for (int i = 0; i < 4; ++i)
                a[i] = *(const bf16x8*)(&As[cur][(wm + i * 16 + l15) * BK + kk * 32 + quad * 8]);
#pragma unroll
            for (int j = 0; j < 4; ++j)
                b[j] = *(const bf16x8*)(&Bs[cur][(wn + j * 16 + l15) * BK + kk * 32 + quad * 8]);
#pragma unroll
            for (int i = 0; i < 4; ++i)
#pragma unroll
                for (int j = 0; j < 4; ++j)
                    acc[i][j] = __builtin_amdgcn_mfma_f32_16x16x32_bf16(a[i], b[j], acc[i][j], 0, 0, 0);
        }
        // one drain per K-step: waits for NEXT tile's loads (issued before MFMA)
        __syncthreads();
    }

    const int slot0 = base[e] + m0;
#pragma unroll
    for (int i = 0; i < 4; ++i) {
#pragma unroll
        for (int r = 0; r < 4; ++r) {
            int row = wm + i * 16 + quad * 4 + r;
            if (m0 + row < cnt) {
                size_t hrow = (size_t)(slot0 + row) * HDIM + n0 + wn;
#pragma unroll
                for (int j = 0; j < 4; ++j)
                    h[hrow + j * 16 + l15] = __float2bfloat16(fmaxf(acc[i][j][r], 0.f));
            }
        }
    }
}

// ---------------- GEMM2: out[tok][:] += w * (h[slot] @ w2[e]) ----------------
// 1-D grid (4096 blocks). Same XCD remap; same T3 min-2-phase double buffer.
__global__ __launch_bounds__(256) void gemm2_kernel(
    const __hip_bfloat16* __restrict__ h, const __hip_bfloat16* __restrict__ w2t,
    const int* __restrict__ counts, const int* __restrict__ base,
    const int* __restrict__ toklist, const float* __restrict__ wglist,
    float* __restrict__ out)
{
    const unsigned bidx = blockIdx.x;
    const unsigned w = (bidx & 7u) * 512u + (bidx >> 3);    // bijective: 4096 % 8 == 0
    const int e  = w >> 9;              // 0..7  (expert == XCD)
    const int m0 = ((w >> 3) & 63) * BM;
    const int n0 = (w & 7) * BN;

    const int cnt = counts[e];
    if (m0 >= cnt) return;

    __shared__ __align__(16) __hip_bfloat16 As[2][BM * BK];
    __shared__ __align__(16) __hip_bfloat16 Bs[2][BN * BK];
    __shared__ int   tok_s[BM];
    __shared__ float wg_s[BM];

    const int tid = threadIdx.x;
    if (tid < BM) {
        int m = m0 + tid;
        tok_s[tid] = (m < cnt) ? toklist[e * CAP + m] : -1;
        wg_s[tid]  = (m < cnt) ? wglist[e * CAP + m] : 0.f;
    }
    __syncthreads();

    const int wave = tid >> 6;
    const int lane = tid & 63;
    const int lrow = lane >> 3;
    const int lcol = (lane & 7) * 8;
    const int slot0 = base[e];
    const __hip_bfloat16* w2e = w2t + (size_t)e * DDIM * HDIM;

    const __hip_bfloat16* srcA[4];
    const __hip_bfloat16* srcB[4];
#pragma unroll
    for (int c = 0; c < 4; ++c) {
        int r = wave * 32 + c * 8 + lrow;
        srcA[c] = h + (size_t)(slot0 + min(m0 + r, cnt - 1)) * HDIM + lcol;
        srcB[c] = w2e + (size_t)(n0 + r) * HDIM + lcol;
    }

    f32x4 acc[4][4];
#pragma unroll
    for (int i = 0; i < 4; ++i)
#pragma unroll
        for (int j = 0; j < 4; ++j) acc[i][j] = (f32x4){0.f, 0.f, 0.f, 0.f};

    const int wm = (wave >> 1) * 64;
    const int wn = (wave & 1) * 64;
    const int l15 = lane & 15;
    const int quad = lane >> 4;

    const int NT = HDIM / BK;   // 64
    // prologue: stage tile 0, drain
#pragma unroll
    for (int c = 0; c < 4; ++c) {
        GLD16(srcA[c], &As[0][(wave * 32 + c * 8) * BK]);
        GLD16(srcB[c], &Bs[0][(wave * 32 + c * 8) * BK]);
    }
    __syncthreads();

    for (int t = 0; t < NT; ++t) {
        const int cur = t & 1;
        if (t + 1 < NT) {
            const int nk = (t + 1) * BK;
#pragma unroll
            for (int c = 0; c < 4; ++c) {
                GLD16(srcA[c] + nk, &As[cur ^ 1][(wave * 32 + c * 8) * BK]);
                GLD16(srcB[c] + nk, &Bs[cur ^ 1][(wave * 32 + c * 8) * BK]);
            }
        }
#pragma unroll
        for (int kk = 0; kk < 2; ++kk) {
            bf16x8 a[4], b[4];
#pragma unroll
            for (int i = 0; i < 4; ++i)
                a[i] = *(const bf16x8*)(&As[cur][(wm + i * 16 + l15) * BK + kk * 32 + quad * 8]);
#pragma unroll
            for (int j = 0; j < 4; ++j)
                b[j] = *(const bf16x8*)(&Bs[cur][(wn + j * 16 + l15) * BK + kk * 32 + quad * 8]);
#pragma unroll
            for (int i = 0; i < 4; ++i)
#pragma unroll
                for (int j = 0; j < 4; ++j)
                    acc[i][j] = __builtin_amdgcn_mfma_f32_16x16x32_bf16(a[i], b[j], acc[i][j], 0, 0, 0);
        }
        __syncthreads();
    }

#pragma unroll
    for (int i = 0; i < 4; ++i) {
#pragma unroll
        for (int r = 0; r < 4; ++r) {
            int row = wm + i * 16 + quad * 4 + r;
            if (m0 + row < cnt) {
                int tok = tok_s[row];
                float wgt = wg_s[row];
                float* orow = out + (size_t)tok * DDIM + n0 + wn;
#pragma unroll
                for (int j = 0; j < 4; ++j)
                    atomicAdd(&orow[j * 16 + l15], wgt * acc[i][j][r]);
            }
        }
    }
}

extern "C" void kernel_launch(void* const* d_in, const int* in_sizes, int n_in,
                              void* d_out, int out_size, void* d_ws, size_t ws_size,
                              hipStream_t stream)
{
    const float* xs = (const float*)d_in[0];   // (B,L,D) fp32
    const float* gw = (const float*)d_in[1];   // (E,D)
    const float* w1 = (const float*)d_in[2];   // (E,D,H)
    const float* w2 = (const float*)d_in[3];   // (E,H,D)
    float* out = (float*)d_out;

    char* ws = (char*)d_ws;
    size_t o = 0;
    int*   counts  = (int*)(ws + o);  o += 256;
    int*   base    = (int*)(ws + o);  o += 256;
    int*   toklist = (int*)(ws + o);  o += (size_t)NEXP * CAP * 4;
    float* wglist  = (float*)(ws + o); o += (size_t)NEXP * CAP * 4;
    __hip_bfloat16* xsb = (__hip_bfloat16*)(ws + o); o += (size_t)NTOK * DDIM * 2;
    __hip_bfloat16* w1t = (__hip_bfloat16*)(ws + o); o += (size_t)NEXP * DDIM * HDIM * 2;
    __hip_bfloat16* w2t = (__hip_bfloat16*)(ws + o); o += (size_t)NEXP * DDIM * HDIM * 2;
    __hip_bfloat16* hbuf = (__hip_bfloat16*)(ws + o); o += (size_t)NSLOT * HDIM * 2;

    hipMemsetAsync(counts, 0, 256, stream);
    hipMemsetAsync(d_out, 0, (size_t)out_size * sizeof(float), stream);

    router_kernel<<<NTOK, 64, 0, stream>>>(xs, gw, counts, toklist, wglist);
    prefix_kernel<<<1, 64, 0, stream>>>(counts, base);
    cvt_xs_kernel<<<(NTOK * DDIM) / (256 * 8), 256, 0, stream>>>(xs, xsb);
    transpose_bf16_kernel<<<dim3(HDIM / 64, DDIM / 64, NEXP), 256, 0, stream>>>(w1, w1t, DDIM, HDIM);
    transpose_bf16_kernel<<<dim3(DDIM / 64, HDIM / 64, NEXP), 256, 0, stream>>>(w2, w2t, HDIM, DDIM);

    gemm1_kernel<<<32 * 64 * NEXP, 256, 0, stream>>>(
        xsb, w1t, counts, base, toklist, hbuf);
    gemm2_kernel<<<8 * 64 * NEXP, 256, 0, stream>>>(
        hbuf, w2t, counts, base, toklist, wglist, out);
}

// Round 4
// 1039.925 us; speedup vs baseline: 1.1894x; 1.1894x over previous
//
#include <hip/hip_runtime.h>
#include <hip/hip_bf16.h>

// Problem constants (B=4, L=2048, D=1024, H=4096, E=8, K=2)
#define NTOK   8192
#define DDIM   1024
#define HDIM   4096
#define NEXP   8
#define CAP    8192
#define NSLOT  (NTOK * 2)

typedef __attribute__((ext_vector_type(8))) short bf16x8;
typedef __attribute__((ext_vector_type(4))) float f32x4;

// async global->LDS, 16B per lane; LDS dest = wave-uniform base + lane*16
#define GLD16(g, l) __builtin_amdgcn_global_load_lds(                          \
    (const __attribute__((address_space(1))) void*)(g),                        \
    (__attribute__((address_space(3))) void*)(l), 16, 0, 0)

// ---------------- Router: logits -> top2 -> softmax -> expert lists ----------------
__global__ __launch_bounds__(64) void router_kernel(
    const float* __restrict__ xs, const float* __restrict__ gw,
    int* __restrict__ counts, int* __restrict__ toklist, float* __restrict__ wglist)
{
    const int n = blockIdx.x;
    const int lane = threadIdx.x;
    const float* xrow = xs + (size_t)n * DDIM;
    float xv[16];
#pragma unroll
    for (int j = 0; j < 16; ++j) xv[j] = xrow[lane + 64 * j];
    float logit[NEXP];
#pragma unroll
    for (int e = 0; e < NEXP; ++e) {
        float p = 0.f;
        const float* gr = gw + e * DDIM;
#pragma unroll
        for (int j = 0; j < 16; ++j) p += xv[j] * gr[lane + 64 * j];
#pragma unroll
        for (int off = 32; off >= 1; off >>= 1) p += __shfl_xor(p, off);
        logit[e] = p;
    }
    if (lane == 0) {
        int i0 = 0;
#pragma unroll
        for (int e = 1; e < NEXP; ++e) if (logit[e] > logit[i0]) i0 = e;
        int i1 = (i0 == 0) ? 1 : 0;
#pragma unroll
        for (int e = 0; e < NEXP; ++e) if (e != i0 && logit[e] > logit[i1]) i1 = e;
        float ex = expf(logit[i1] - logit[i0]);
        float w0 = 1.f / (1.f + ex);
        float w1 = ex * w0;
        int p0 = atomicAdd(&counts[i0], 1);
        toklist[i0 * CAP + p0] = n;
        wglist[i0 * CAP + p0] = w0;
        int p1 = atomicAdd(&counts[i1], 1);
        toklist[i1 * CAP + p1] = n;
        wglist[i1 * CAP + p1] = w1;
    }
}

__global__ void prefix_kernel(const int* __restrict__ counts, int* __restrict__ base)
{
    if (threadIdx.x == 0 && blockIdx.x == 0) {
        int s = 0;
        for (int e = 0; e < NEXP; ++e) { base[e] = s; s += counts[e]; }
    }
}

// ---------------- xs fp32 -> bf16 ----------------
__global__ __launch_bounds__(256) void cvt_xs_kernel(
    const float* __restrict__ xs, __hip_bfloat16* __restrict__ xsb)
{
    const size_t i = ((size_t)blockIdx.x * 256 + threadIdx.x) * 8;
    const float4 a = *(const float4*)(xs + i);
    const float4 b = *(const float4*)(xs + i + 4);
    __hip_bfloat16 o[8];
    o[0] = __float2bfloat16(a.x); o[1] = __float2bfloat16(a.y);
    o[2] = __float2bfloat16(a.z); o[3] = __float2bfloat16(a.w);
    o[4] = __float2bfloat16(b.x); o[5] = __float2bfloat16(b.y);
    o[6] = __float2bfloat16(b.z); o[7] = __float2bfloat16(b.w);
    *(bf16x8*)(xsb + i) = *(bf16x8*)o;
}

// ---------------- per-expert transpose fp32 (RxC) -> bf16 (CxR) ----------------
__global__ __launch_bounds__(256) void transpose_bf16_kernel(
    const float* __restrict__ src, __hip_bfloat16* __restrict__ dst, int R, int C)
{
    __shared__ __hip_bfloat16 t[64][72];
    const int e = blockIdx.z;
    src += (size_t)e * R * C;
    dst += (size_t)e * R * C;
    const int r0 = blockIdx.y * 64, c0 = blockIdx.x * 64;
    const int tid = threadIdx.x;
#pragma unroll
    for (int i = 0; i < 4; ++i) {
        int r = (tid >> 4) + 16 * i;
        int c = (tid & 15) * 4;
        float4 v = *(const float4*)(src + (size_t)(r0 + r) * C + c0 + c);
        t[r][c + 0] = __float2bfloat16(v.x);
        t[r][c + 1] = __float2bfloat16(v.y);
        t[r][c + 2] = __float2bfloat16(v.z);
        t[r][c + 3] = __float2bfloat16(v.w);
    }
    __syncthreads();
#pragma unroll
    for (int i = 0; i < 4; ++i) {
        int c = (tid >> 4) + 16 * i;
        int r = (tid & 15) * 4;
        __hip_bfloat16 o[4] = { t[r][c], t[r + 1][c], t[r + 2][c], t[r + 3][c] };
        *(short4*)(dst + (size_t)(c0 + c) * R + r0 + r) = *(short4*)o;
    }
}

// =====================================================================
// 256x256 8-phase grouped GEMM (T2 swizzle + T3/T4 counted vmcnt + T5 setprio)
//   A: [rows][KD] bf16 (gemm1: gathered by token; gemm2: slot-contiguous h)
//   B: [ND][KD]  bf16 (w-transposed)
//   8 waves (2M x 4N), per-wave C = 128x64, BK=64, LDS exactly 128 KiB.
// Pipeline ledger (2 loads/STAGE): prologue issues 10, VM2 drains to 2;
// each P adds 2; P4/P8 VM2 drains 8 = exactly the buffer about to be read.
// =====================================================================

#define BAR()   __builtin_amdgcn_s_barrier()
#define LGKM0() do { asm volatile("s_waitcnt lgkmcnt(0)" ::: "memory"); \
                     __builtin_amdgcn_sched_barrier(0); } while (0)
#define VM2()   do { asm volatile("s_waitcnt vmcnt(2)" ::: "memory");   \
                     __builtin_amdgcn_sched_barrier(0); } while (0)

#define LDS_A(buf, mi, kk) \
    (*(const bf16x8*)((const char*)(&As[buf][wr][0]) + (((mi) * 16 + l15) * 128) + cbk[kk]))
#define LDS_B(buf, nj, kk) \
    (*(const bf16x8*)((const char*)(&Bs[buf][bh][0]) + ((brow0 + (nj) * 16 + l15) * 128) + cbk[kk]))

#define LDA4(buf, mib) do {                                              \
    _Pragma("unroll") for (int i_ = 0; i_ < 4; ++i_) {                   \
        aR[i_][0] = LDS_A(buf, (mib) + i_, 0);                           \
        aR[i_][1] = LDS_A(buf, (mib) + i_, 1); } } while (0)

#define LDB2(buf, njb) do {                                              \
    _Pragma("unroll") for (int j_ = 0; j_ < 2; ++j_) {                   \
        bR[(njb) + j_][0] = LDS_B(buf, (njb) + j_, 0);                   \
        bR[(njb) + j_][1] = LDS_B(buf, (njb) + j_, 1); } } while (0)

#define MFMA16(ib, jb) do {                                              \
    __builtin_amdgcn_s_setprio(1);                                       \
    _Pragma("unroll") for (int i_ = 0; i_ < 4; ++i_)                     \
    _Pragma("unroll") for (int j_ = 0; j_ < 2; ++j_) {                   \
        acc[(ib) + i_][(jb) + j_] = __builtin_amdgcn_mfma_f32_16x16x32_bf16( \
            aR[i_][0], bR[(jb) + j_][0], acc[(ib) + i_][(jb) + j_], 0, 0, 0); \
        acc[(ib) + i_][(jb) + j_] = __builtin_amdgcn_mfma_f32_16x16x32_bf16( \
            aR[i_][1], bR[(jb) + j_][1], acc[(ib) + i_][(jb) + j_], 0, 0, 0); } \
    __builtin_amdgcn_s_setprio(0); } while (0)

#define STAGE(bb, hx, tt) do {                                           \
    const int kb_ = min((tt), NT - 1) * 128;                             \
    if ((hx) < 2) {                                                      \
        GLD16(pA[hx][0] + kb_, &As[bb][hx][ldsr0]);                      \
        GLD16(pA[hx][1] + kb_, &As[bb][hx][ldsr1]);                      \
    } else {                                                             \
        GLD16(pB[(hx) - 2][0] + kb_, &Bs[bb][(hx) - 2][ldsr0]);          \
        GLD16(pB[(hx) - 2][1] + kb_, &Bs[bb][(hx) - 2][ldsr1]); } } while (0)

template<int IS_G2>
__global__ __launch_bounds__(512, 2) void gemm8p_kernel(
    const __hip_bfloat16* __restrict__ Aglob, const __hip_bfloat16* __restrict__ Bglob,
    const int* __restrict__ counts, const int* __restrict__ base,
    const int* __restrict__ toklist, const float* __restrict__ wglist,
    __hip_bfloat16* __restrict__ hout, float* __restrict__ fout)
{
    constexpr int KD  = IS_G2 ? HDIM : DDIM;   // k length of A/B rows
    constexpr int ND  = IS_G2 ? DDIM : HDIM;   // output width
    constexpr int NT  = KD / 64;               // K-tiles
    constexpr int NTB = ND / 256;              // n-tiles

    // XCD-bijective remap: XCD k == expert k; n fastest for A-panel L2 reuse.
    const unsigned chunk = 32u * NTB;          // blocks per expert (CAP/256 m-tiles)
    const unsigned wg = (blockIdx.x & 7u) * chunk + (blockIdx.x >> 3);
    const int e  = wg / chunk;
    const unsigned rem = wg % chunk;
    const int m0 = (int)(rem / NTB) * 256;
    const int n0 = (int)(rem % NTB) * 256;

    const int cnt = counts[e];
    if (m0 >= cnt) return;

    // LDS = exactly 128 KiB (no extra arrays: keeps the verified m201 footprint)
    __shared__ __align__(16) __hip_bfloat16 As[2][2][128 * 64];
    __shared__ __align__(16) __hip_bfloat16 Bs[2][2][128 * 64];

    const int tid  = threadIdx.x;
    const int wid  = tid >> 6;
    const int lane = tid & 63;
    const int wr   = wid >> 2;                 // 0..1  A half
    const int wc   = wid & 3;                  // 0..3
    const int bh   = wc >> 1;                  // B half
    const int brow0 = (wc & 1) * 64;           // B row base within half
    const int l15  = lane & 15;
    const int quad = lane >> 4;

    // ---- staging source pointers (swizzle folded into the GLOBAL address, rule 21) ----
    const int srow8 = lane >> 3;                                     // 0..7
    const int cswz  = ((lane & 7) * 16) ^ (srow8 << 4);
    const int ldsr0 = (wid * 16 + 0) * 64;                           // wave-uniform LDS bases
    const int ldsr1 = (wid * 16 + 8) * 64;
    const __hip_bfloat16* Be = Bglob + (size_t)e * ND * KD;
    const int slot0 = base[e];

    const char* pA[2][2];
    const char* pB[2][2];
#pragma unroll
    for (int hh = 0; hh < 2; ++hh)
#pragma unroll
        for (int ii = 0; ii < 2; ++ii) {
            const int lr = hh * 128 + wid * 16 + ii * 8 + srow8;     // local row 0..255
            size_t arow;
            if (IS_G2) arow = (size_t)(slot0 + min(m0 + lr, cnt - 1));
            else       arow = (size_t)toklist[e * CAP + min(m0 + lr, cnt - 1)];
            pA[hh][ii] = (const char*)(Aglob + arow * KD) + cswz;
            pB[hh][ii] = (const char*)(Be + (size_t)(n0 + lr) * KD) + cswz;
        }

    // ---- fragment read byte-offsets (swizzled; row&7 == l15&7 for all frags) ----
    int cbk[2];
    cbk[0] = (quad * 16) ^ ((l15 & 7) << 4);
    cbk[1] = (64 + quad * 16) ^ ((l15 & 7) << 4);

    f32x4 acc[8][4];
#pragma unroll
    for (int i = 0; i < 8; ++i)
#pragma unroll
        for (int j = 0; j < 4; ++j) acc[i][j] = (f32x4){0.f, 0.f, 0.f, 0.f};
    bf16x8 aR[4][2], bR[4][2];

    // ---- prologue: tile0 (4 halves) + tile1 h0; wait tile0, keep 1 half in flight ----
    STAGE(0, 0, 0); STAGE(0, 1, 0); STAGE(0, 2, 0); STAGE(0, 3, 0);
    STAGE(1, 0, 1);
    VM2();
    BAR();

#pragma unroll 1
    for (int it = 0; it < NT / 2; ++it) {
        const int T = 2 * it;
        // ---- P1: tile T (buf0), quadrant mi0-3 x nj0-1 ----
        LDA4(0, 0); LDB2(0, 0); STAGE(1, 1, T + 1);
        BAR(); LGKM0(); MFMA16(0, 0); BAR();
        // ---- P2: mi0-3 x nj2-3 ----
        LDB2(0, 2); STAGE(1, 2, T + 1);
        BAR(); LGKM0(); MFMA16(0, 2); BAR();
        // ---- P3: mi4-7 x nj2-3 ----
        LDA4(0, 4); STAGE(1, 3, T + 1);
        BAR(); LGKM0(); MFMA16(4, 2); BAR();
        // ---- P4: mi4-7 x nj0-1 (regs held from P1/P3); vmcnt covers tile T+1 ----
        STAGE(0, 0, T + 2); VM2();
        BAR(); MFMA16(4, 0); BAR();
        // ---- P5: tile T+1 (buf1), mi0-3 x nj0-1 ----
        LDA4(1, 0); LDB2(1, 0); STAGE(0, 1, T + 2);
        BAR(); LGKM0(); MFMA16(0, 0); BAR();
        // ---- P6 ----
        LDB2(1, 2); STAGE(0, 2, T + 2);
        BAR(); LGKM0(); MFMA16(0, 2); BAR();
        // ---- P7 ----
        LDA4(1, 4); STAGE(0, 3, T + 2);
        BAR(); LGKM0(); MFMA16(4, 2); BAR();
        // ---- P8: vmcnt covers tile T+2 for next iteration ----
        STAGE(1, 0, T + 3); VM2();
        BAR(); MFMA16(4, 0); BAR();
    }

    // ---- epilogue (token/weight read straight from global; L1/L2-resident) ----
    if (IS_G2) {
#pragma unroll
        for (int mi = 0; mi < 8; ++mi)
#pragma unroll
            for (int r = 0; r < 4; ++r) {
                const int row = wr * 128 + mi * 16 + quad * 4 + r;
                if (m0 + row < cnt) {
                    const int tok   = toklist[e * CAP + m0 + row];
                    const float wgt = wglist[e * CAP + m0 + row];
                    float* orow = fout + (size_t)tok * DDIM + n0 + wc * 64;
#pragma unroll
                    for (int nj = 0; nj < 4; ++nj)
                        atomicAdd(&orow[nj * 16 + l15], wgt * acc[mi][nj][r]);
                }
            }
    } else {
#pragma unroll
        for (int mi = 0; mi < 8; ++mi)
#pragma unroll
            for (int r = 0; r < 4; ++r) {
                const int row = wr * 128 + mi * 16 + quad * 4 + r;
                if (m0 + row < cnt) {
                    size_t orow = (size_t)(slot0 + m0 + row) * HDIM + n0 + wc * 64;
#pragma unroll
                    for (int nj = 0; nj < 4; ++nj)
                        hout[orow + nj * 16 + l15] =
                            __float2bfloat16(fmaxf(acc[mi][nj][r], 0.f));
                }
            }
    }
}

extern "C" void kernel_launch(void* const* d_in, const int* in_sizes, int n_in,
                              void* d_out, int out_size, void* d_ws, size_t ws_size,
                              hipStream_t stream)
{
    const float* xs = (const float*)d_in[0];   // (B,L,D) fp32
    const float* gw = (const float*)d_in[1];   // (E,D)
    const float* w1 = (const float*)d_in[2];   // (E,D,H)
    const float* w2 = (const float*)d_in[3];   // (E,H,D)
    float* out = (float*)d_out;

    char* ws = (char*)d_ws;
    size_t o = 0;
    int*   counts  = (int*)(ws + o);  o += 256;
    int*   base    = (int*)(ws + o);  o += 256;
    int*   toklist = (int*)(ws + o);  o += (size_t)NEXP * CAP * 4;
    float* wglist  = (float*)(ws + o); o += (size_t)NEXP * CAP * 4;
    __hip_bfloat16* xsb = (__hip_bfloat16*)(ws + o); o += (size_t)NTOK * DDIM * 2;
    __hip_bfloat16* w1t = (__hip_bfloat16*)(ws + o); o += (size_t)NEXP * DDIM * HDIM * 2;
    __hip_bfloat16* w2t = (__hip_bfloat16*)(ws + o); o += (size_t)NEXP * DDIM * HDIM * 2;
    __hip_bfloat16* hbuf = (__hip_bfloat16*)(ws + o); o += (size_t)NSLOT * HDIM * 2;

    hipMemsetAsync(counts, 0, 256, stream);
    hipMemsetAsync(d_out, 0, (size_t)out_size * sizeof(float), stream);

    router_kernel<<<NTOK, 64, 0, stream>>>(xs, gw, counts, toklist, wglist);
    prefix_kernel<<<1, 64, 0, stream>>>(counts, base);
    cvt_xs_kernel<<<(NTOK * DDIM) / (256 * 8), 256, 0, stream>>>(xs, xsb);
    transpose_bf16_kernel<<<dim3(HDIM / 64, DDIM / 64, NEXP), 256, 0, stream>>>(w1, w1t, DDIM, HDIM);
    transpose_bf16_kernel<<<dim3(DDIM / 64, HDIM / 64, NEXP), 256, 0, stream>>>(w2, w2t, HDIM, DDIM);

    // grid = NEXP * (CAP/256 m-tiles) * n-tiles; divisible by 8 (XCD remap)
    gemm8p_kernel<0><<<NEXP * 32 * (HDIM / 256), 512, 0, stream>>>(
        xsb, w1t, counts, base, toklist, wglist, hbuf, nullptr);
    gemm8p_kernel<1><<<NEXP * 32 * (DDIM / 256), 512, 0, stream>>>(
        hbuf, w2t, counts, base, toklist, wglist, nullptr, out);
}